// Round 10
// baseline (564.339 us; speedup 1.0000x reference)
//
#include <hip/hip_runtime.h>
#include <hip/hip_bf16.h>

typedef float  f32x4  __attribute__((ext_vector_type(4)));
typedef __bf16 bf16x8 __attribute__((ext_vector_type(8)));
typedef __bf16 bf16x4 __attribute__((ext_vector_type(4)));

#define Bz 4
#define Tz 2048
#define Cz 2048
#define Hh 16
#define Dd 128
#define Mm 8192   // B*T

__device__ __forceinline__ void gload_lds16(const __bf16* g, __bf16* l) {
  __builtin_amdgcn_global_load_lds(
      (const __attribute__((address_space(1))) void*)g,
      (__attribute__((address_space(3))) void*)l, 16, 0, 0);
}

// ---------------- f32 -> bf16 convert (vectorized) ----------------
__global__ __launch_bounds__(256)
void cvt_bf16(const float* __restrict__ in, __bf16* __restrict__ out, int n8) {
  int i = blockIdx.x * 256 + threadIdx.x;
  if (i >= n8) return;
  size_t base = (size_t)i * 8;
  f32x4 a = *(const f32x4*)(in + base);
  f32x4 b = *(const f32x4*)(in + base + 4);
  bf16x8 o;
  o[0]=(__bf16)a[0]; o[1]=(__bf16)a[1]; o[2]=(__bf16)a[2]; o[3]=(__bf16)a[3];
  o[4]=(__bf16)b[0]; o[5]=(__bf16)b[1]; o[6]=(__bf16)b[2]; o[7]=(__bf16)b[3];
  *(bf16x8*)(out + base) = o;
}

// ---------------- GEMM: C = A @ W^T + bias (proven 128^2 structure) ----------
// A [M][K] bf16 row-major, W [N][K] bf16 row-major (torch Linear weight).
// MODE 0: out bf16 scattered to [B*H][T][D], value = (acc+bias)*scale
// MODE 1: out f32 [M][N], value = acc + bias
// MODE 2: out bf16 scattered to [B*H][D][T] (transposed, for V)
template<int MODE>
__global__ __launch_bounds__(256, 3)
void gemm_bt(const __bf16* __restrict__ A, const __bf16* __restrict__ W,
             const float* __restrict__ bias, void* __restrict__ Out,
             int K, float scale)
{
  __shared__ __bf16 As[128 * 64];
  __shared__ __bf16 Bs[128 * 64];

  const int tid  = threadIdx.x;
  const int lane = tid & 63;
  const int wave = tid >> 6;
  const int wm = wave >> 1, wn = wave & 1;
  const int g  = lane >> 4;
  const int lr = lane & 15;
  const int row0 = blockIdx.x * 128;
  const int col0 = blockIdx.y * 128;

  const int srow = lane >> 3;   // 0..7 within 8-row stripe
  const int sblk = lane & 7;    // 16B block within row

  f32x4 acc[4][4] = {};

  for (int kt = 0; kt < K; kt += 64) {
    __syncthreads();
    #pragma unroll
    for (int p = 0; p < 4; ++p) {
      const int rb = p * 32 + wave * 8;
      const int r  = rb + srow;
      const int cb = sblk ^ (r & 7);   // pre-swizzled global source (linear LDS dest)
      gload_lds16(A + (size_t)(row0 + r) * K + kt + cb * 8, As + rb * 64);
      gload_lds16(W + (size_t)(col0 + r) * K + kt + cb * 8, Bs + rb * 64);
    }
    __syncthreads();
    #pragma unroll
    for (int kk = 0; kk < 2; ++kk) {
      bf16x8 af[4], bfr[4];
      #pragma unroll
      for (int i = 0; i < 4; ++i) {
        const int ar = wm * 64 + i * 16 + lr;
        af[i]  = *(const bf16x8*)(As + ar * 64 + ((((kk<<2)|g) ^ (ar & 7)) << 3));
        const int br = wn * 64 + i * 16 + lr;
        bfr[i] = *(const bf16x8*)(Bs + br * 64 + ((((kk<<2)|g) ^ (br & 7)) << 3));
      }
      #pragma unroll
      for (int i = 0; i < 4; ++i)
        #pragma unroll
        for (int j = 0; j < 4; ++j)
          acc[i][j] = __builtin_amdgcn_mfma_f32_16x16x32_bf16(af[i], bfr[j], acc[i][j], 0, 0, 0);
    }
  }

  #pragma unroll
  for (int j = 0; j < 4; ++j) {
    const int col = col0 + wn * 64 + j * 16 + lr;
    const float bv = bias[col];
    #pragma unroll
    for (int i = 0; i < 4; ++i) {
      if (MODE == 2) {
        // V^T layout: Vt[(pair*D + d)*T + t]; 4 consecutive t per lane -> 8B store
        const int row = row0 + wm * 64 + i * 16 + g * 4;   // first of 4 rows
        const int b = row >> 11, t = row & (Tz - 1);
        const int h = col >> 7,  d = col & (Dd - 1);
        bf16x4 v4;
        #pragma unroll
        for (int r = 0; r < 4; ++r) v4[r] = (__bf16)(acc[i][j][r] + bv);
        *(bf16x4*)((__bf16*)Out + ((size_t)(b * Hh + h) * Dd + d) * Tz + t) = v4;
      } else {
        #pragma unroll
        for (int r = 0; r < 4; ++r) {
          const int row = row0 + wm * 64 + i * 16 + g * 4 + r;
          const float v = acc[i][j][r] + bv;
          if (MODE == 0) {
            const int b = row >> 11, t = row & (Tz - 1);
            const int h = col >> 7,  d = col & (Dd - 1);
            ((__bf16*)Out)[((size_t)(b * Hh + h) * Tz + t) * Dd + d] = (__bf16)(v * scale);
          } else {
            ((float*)Out)[(size_t)row * Cz + col] = v;
          }
        }
      }
    }
  }
}

// ---------------- causal flash attention (swapped QK^T, KVBLK=32) -------------
// Q,K: [B*H][T][D] bf16 (Q pre-scaled by log2(e)/sqrt(D)). Vt: [B*H][D][T] bf16.
// O: [B*T][C] bf16. Softmax in exp2 domain, in-register per q-row (q = lr).
// KV tile = 32 -> LDS 40KB -> 4 blocks/CU (16 waves) for latency hiding.
// Grid (pair, qslot): pair FAST (same-KV blocks share XCD); qt = 15 - slot so
// the longest blocks dispatch first (LPT-style balance, 1024 blocks on 256 CU).
__global__ __launch_bounds__(256, 4)
void attn_fwd(const __bf16* __restrict__ Q, const __bf16* __restrict__ Kg,
              const __bf16* __restrict__ Vt, __bf16* __restrict__ O)
{
  __shared__ __bf16 Ks[2][32 * 128];   // [kv][d], 16B-slot XOR swizzle by (kv&7)
  __shared__ __bf16 Vs[2][128 * 32];   // [d][kv], 16B-slot XOR swizzle by (d&3)
  __shared__ __bf16 Ps[4][32 * 32];    // per-wave P [32 q][32 kv], 8B-quad XOR by (q&3)<<1

  const int tid  = threadIdx.x;
  const int lane = tid & 63;
  const int wave = tid >> 6;
  const int g  = lane >> 4;
  const int lr = lane & 15;
  const int pair = blockIdx.x;        // b*H + h  (FAST dim -> same-KV blocks share XCD)
  const int qt   = 15 - (int)blockIdx.y;
  const int b = pair >> 4, h = pair & 15;

  const __bf16* Qp = Q  + (size_t)pair * Tz * Dd;
  const __bf16* Kp = Kg + (size_t)pair * Tz * Dd;
  const __bf16* Vp = Vt + (size_t)pair * Dd * Tz;

  #define STAGE_KV(kv0_, buf_)                                                  \
    {                                                                           \
      const int kv0s = (kv0_);                                                  \
      _Pragma("unroll")                                                         \
      for (int p = 0; p < 2; ++p) {                                             \
        const int r  = p * 16 + wave * 4 + (lane >> 4);                         \
        const int cb = (lane & 15) ^ (r & 7);                                   \
        gload_lds16(Kp + (size_t)(kv0s + r) * Dd + cb * 8,                      \
                    &Ks[buf_][p * 2048 + wave * 512]);                          \
        const int d  = p * 64 + wave * 16 + (lane >> 2);                        \
        const int cv = (lane & 3) ^ (d & 3);                                    \
        gload_lds16(Vp + (size_t)d * Tz + kv0s + cv * 8,                        \
                    &Vs[buf_][p * 2048 + wave * 512]);                          \
      }                                                                         \
    }

  const int qw0 = qt * 128 + wave * 32;

  // Q fragments in registers (rows qw0..qw0+31)
  bf16x8 qf[2][4];
  #pragma unroll
  for (int im = 0; im < 2; ++im)
    #pragma unroll
    for (int ks = 0; ks < 4; ++ks)
      qf[im][ks] = *(const bf16x8*)(Qp + (size_t)(qw0 + im*16 + lr) * Dd + ks*32 + g*8);

  f32x4 oacc[2][8] = {};          // O[q = g*4+r][d = dn*16+lr]
  float mrow[2], lsum[2];         // per-lane holder for q-row = qw0 + im*16 + lr
  mrow[0] = mrow[1] = -1e30f;
  lsum[0] = lsum[1] = 0.f;

  const int ntiles = 4 * qt + 4;

  STAGE_KV(0, 0);
  __syncthreads();   // drains prologue loads

  for (int kt = 0; kt < ntiles; ++kt) {
    const int cur = kt & 1;
    const int kv0 = kt * 32;
    if (kt + 1 < ntiles) STAGE_KV((kt + 1) * 32, cur ^ 1);

    if (kv0 <= qw0 + 31) {
      // ---- S^T = K Q^T : lane holds q = qw0+im*16+lr, kv = kv0+in*16+g*4+r ----
      f32x4 sacc[2][2] = {};
      __builtin_amdgcn_s_setprio(1);
      #pragma unroll
      for (int ks = 0; ks < 4; ++ks) {
        bf16x8 kf[2];
        #pragma unroll
        for (int in = 0; in < 2; ++in) {
          const int r = in*16 + lr;
          kf[in] = *(const bf16x8*)(&Ks[cur][r * 128 + ((((ks<<2)|g) ^ (r & 7)) << 3)]);
        }
        #pragma unroll
        for (int im = 0; im < 2; ++im)
          #pragma unroll
          for (int in = 0; in < 2; ++in)
            sacc[im][in] = __builtin_amdgcn_mfma_f32_16x16x32_bf16(kf[in], qf[im][ks], sacc[im][in], 0, 0, 0);
      }
      __builtin_amdgcn_s_setprio(0);

      // ---- causal mask (diagonal tiles only) ----
      if (kv0 + 31 > qw0) {
        #pragma unroll
        for (int im = 0; im < 2; ++im) {
          const int q = qw0 + im*16 + lr;
          #pragma unroll
          for (int in = 0; in < 2; ++in)
            #pragma unroll
            for (int r = 0; r < 4; ++r) {
              const int kv = kv0 + in*16 + g*4 + r;
              if (kv > q) sacc[im][in][r] = -3e38f;
            }
        }
      }

      // ---- online softmax, in-register (exp2 domain, defer-max 8 nats) ----
      #pragma unroll
      for (int im = 0; im < 2; ++im) {
        float m = fmaxf(fmaxf(sacc[im][0][0], sacc[im][0][1]),
                        fmaxf(sacc[im][0][2], sacc[im][0][3]));
        m = fmaxf(m, fmaxf(fmaxf(sacc[im][1][0], sacc[im][1][1]),
                           fmaxf(sacc[im][1][2], sacc[im][1][3])));
        m = fmaxf(m, __shfl_xor(m, 16));
        m = fmaxf(m, __shfl_xor(m, 32));

        const bool need = m > mrow[im] + 11.54f;
        if (__any(need)) {
          const float mn   = need ? m : mrow[im];
          const float corr = __builtin_amdgcn_exp2f(mrow[im] - mn);
          mrow[im] = mn;
          lsum[im] *= corr;
          const int sb = 20 * g;             // srcLane = 16g + (4g+r)
          const float c0 = __shfl(corr, sb + 0);
          const float c1 = __shfl(corr, sb + 1);
          const float c2 = __shfl(corr, sb + 2);
          const float c3 = __shfl(corr, sb + 3);
          #pragma unroll
          for (int dn = 0; dn < 8; ++dn) {
            oacc[im][dn][0] *= c0; oacc[im][dn][1] *= c1;
            oacc[im][dn][2] *= c2; oacc[im][dn][3] *= c3;
          }
        }

        float rs = 0.f;
        const int prow = im*16 + lr;
        const int pkey = (prow & 3) << 1;    // even key: keeps quad pairs adjacent
        #pragma unroll
        for (int in = 0; in < 2; ++in) {
          const float p0 = __builtin_amdgcn_exp2f(sacc[im][in][0] - mrow[im]);
          const float p1 = __builtin_amdgcn_exp2f(sacc[im][in][1] - mrow[im]);
          const float p2 = __builtin_amdgcn_exp2f(sacc[im][in][2] - mrow[im]);
          const float p3 = __builtin_amdgcn_exp2f(sacc[im][in][3] - mrow[im]);
          rs += (p0 + p1) + (p2 + p3);
          bf16x4 q4;
          q4[0] = (__bf16)p0; q4[1] = (__bf16)p1;
          q4[2] = (__bf16)p2; q4[3] = (__bf16)p3;
          const int bs = (in*4 + g) ^ pkey;  // 8 quads/row
          *(bf16x4*)(&Ps[wave][prow * 32 + bs * 4]) = q4;
        }
        rs += __shfl_xor(rs, 16);
        rs += __shfl_xor(rs, 32);
        lsum[im] += rs;
      }

      // ---- O += P V ----
      __builtin_amdgcn_s_setprio(1);
      {
        bf16x8 pa[2];
        #pragma unroll
        for (int im = 0; im < 2; ++im) {
          const int prow = im*16 + lr;
          const int bs = (2*g) ^ ((prow & 3) << 1);
          pa[im] = *(const bf16x8*)(&Ps[wave][prow * 32 + bs * 4]);
        }
        #pragma unroll
        for (int dn = 0; dn < 8; ++dn) {
          const int d = dn*16 + lr;
          bf16x8 vb = *(const bf16x8*)(&Vs[cur][d * 32 + ((g ^ (d & 3)) << 3)]);
          #pragma unroll
          for (int im = 0; im < 2; ++im)
            oacc[im][dn] = __builtin_amdgcn_mfma_f32_16x16x32_bf16(pa[im], vb, oacc[im][dn], 0, 0, 0);
        }
      }
      __builtin_amdgcn_s_setprio(0);
    }
    __syncthreads();   // publishes buf[cur^1] stages; protects buf[cur] reuse
  }

  // ---- epilogue: O[b*T+q][h*D+d] = oacc / lsum ----
  #pragma unroll
  for (int im = 0; im < 2; ++im) {
    const float inv = 1.0f / lsum[im];      // holder lanes: q = lr
    const int sb = 20 * g;
    const float i0 = __shfl(inv, sb + 0);
    const float i1 = __shfl(inv, sb + 1);
    const float i2 = __shfl(inv, sb + 2);
    const float i3 = __shfl(inv, sb + 3);
    #pragma unroll
    for (int dn = 0; dn < 8; ++dn) {
      const int qrow = qw0 + im*16 + g*4;
      const int d    = h * Dd + dn*16 + lr;
      O[((size_t)(b * Tz + qrow + 0)) * Cz + d] = (__bf16)(oacc[im][dn][0] * i0);
      O[((size_t)(b * Tz + qrow + 1)) * Cz + d] = (__bf16)(oacc[im][dn][1] * i1);
      O[((size_t)(b * Tz + qrow + 2)) * Cz + d] = (__bf16)(oacc[im][dn][2] * i2);
      O[((size_t)(b * Tz + qrow + 3)) * Cz + d] = (__bf16)(oacc[im][dn][3] * i3);
    }
  }
  #undef STAGE_KV
}

// ---------------- host launcher ----------------
extern "C" void kernel_launch(void* const* d_in, const int* in_sizes, int n_in,
                              void* d_out, int out_size, void* d_ws, size_t ws_size,
                              hipStream_t stream) {
  const float* x  = (const float*)d_in[0];
  const float* wq = (const float*)d_in[1];
  const float* bq = (const float*)d_in[2];
  const float* wk = (const float*)d_in[3];
  const float* bk = (const float*)d_in[4];
  const float* wv = (const float*)d_in[5];
  const float* bv = (const float*)d_in[6];
  const float* wo = (const float*)d_in[7];
  const float* bo = (const float*)d_in[8];
  float* out = (float*)d_out;

  char* w = (char*)d_ws;
  __bf16* xb   = (__bf16*)w; w += (size_t)Mm * Cz * 2;   // x bf16; reused as attn-out later
  __bf16* wbuf = (__bf16*)w; w += (size_t)Cz * Cz * 2;   // current weight bf16
  __bf16* qb   = (__bf16*)w; w += (size_t)Mm * Cz * 2;
  __bf16* kb   = (__bf16*)w; w += (size_t)Mm * Cz * 2;
  __bf16* vbuf = (__bf16*)w; w += (size_t)Mm * Cz * 2;
  if (ws_size < (size_t)(w - (char*)d_ws)) return;  // workspace too small: fail loudly

  const int nx8 = Mm * Cz / 8;   // 2,097,152
  const int nw8 = Cz * Cz / 8;   //   524,288
  dim3 ggrid(Mm / 128, Cz / 128);
  // 1/sqrt(128) * log2(e): softmax runs in exp2 domain
  const float qscale = 0.12752551286084110f;

  cvt_bf16<<<nx8 / 256, 256, 0, stream>>>(x, xb, nx8);

  cvt_bf16<<<nw8 / 256, 256, 0, stream>>>(wq, wbuf, nw8);
  gemm_bt<0><<<ggrid, 256, 0, stream>>>(xb, wbuf, bq, qb, Cz, qscale);

  cvt_bf16<<<nw8 / 256, 256, 0, stream>>>(wk, wbuf, nw8);
  gemm_bt<0><<<ggrid, 256, 0, stream>>>(xb, wbuf, bk, kb, Cz, 1.0f);

  cvt_bf16<<<nw8 / 256, 256, 0, stream>>>(wv, wbuf, nw8);
  gemm_bt<2><<<ggrid, 256, 0, stream>>>(xb, wbuf, bv, vbuf, Cz, 1.0f);  // writes V^T

  // attention writes its output over xb (x no longer needed)
  __bf16* ob = xb;
  attn_fwd<<<dim3(Bz * Hh, 16), 256, 0, stream>>>(qb, kb, vbuf, ob);

  cvt_bf16<<<nw8 / 256, 256, 0, stream>>>(wo, wbuf, nw8);
  gemm_bt<1><<<ggrid, 256, 0, stream>>>(ob, wbuf, bo, out, Cz, 1.0f);
}

// Round 11
// 385.493 us; speedup vs baseline: 1.4639x; 1.4639x over previous
//
#include <hip/hip_runtime.h>
#include <hip/hip_bf16.h>

typedef float  f32x4  __attribute__((ext_vector_type(4)));
typedef __bf16 bf16x8 __attribute__((ext_vector_type(8)));
typedef __bf16 bf16x4 __attribute__((ext_vector_type(4)));

#define Bz 4
#define Tz 2048
#define Cz 2048
#define Hh 16
#define Dd 128
#define Mm 8192   // B*T

__device__ __forceinline__ void gload_lds16(const __bf16* g, __bf16* l) {
  __builtin_amdgcn_global_load_lds(
      (const __attribute__((address_space(1))) void*)g,
      (__attribute__((address_space(3))) void*)l, 16, 0, 0);
}

// ---------------- f32 -> bf16 convert (vectorized) ----------------
__global__ __launch_bounds__(256)
void cvt_bf16(const float* __restrict__ in, __bf16* __restrict__ out, int n8) {
  int i = blockIdx.x * 256 + threadIdx.x;
  if (i >= n8) return;
  size_t base = (size_t)i * 8;
  f32x4 a = *(const f32x4*)(in + base);
  f32x4 b = *(const f32x4*)(in + base + 4);
  bf16x8 o;
  o[0]=(__bf16)a[0]; o[1]=(__bf16)a[1]; o[2]=(__bf16)a[2]; o[3]=(__bf16)a[3];
  o[4]=(__bf16)b[0]; o[5]=(__bf16)b[1]; o[6]=(__bf16)b[2]; o[7]=(__bf16)b[3];
  *(bf16x8*)(out + base) = o;
}

// all 4 weights in one launch: wq/wk/wv -> wqkv (contiguous), wo -> wob
__global__ __launch_bounds__(256)
void cvt_w4(const float* __restrict__ w0, const float* __restrict__ w1,
            const float* __restrict__ w2, const float* __restrict__ w3,
            __bf16* __restrict__ wqkv, __bf16* __restrict__ wob) {
  const int n8 = Cz * Cz / 8;
  int i = blockIdx.x * 256 + threadIdx.x;
  if (i >= n8) return;
  const int which = blockIdx.y;
  const float* src = which == 0 ? w0 : which == 1 ? w1 : which == 2 ? w2 : w3;
  __bf16* dst = which == 3 ? wob : wqkv + (size_t)which * Cz * Cz;
  size_t base = (size_t)i * 8;
  f32x4 a = *(const f32x4*)(src + base);
  f32x4 b = *(const f32x4*)(src + base + 4);
  bf16x8 o;
  o[0]=(__bf16)a[0]; o[1]=(__bf16)a[1]; o[2]=(__bf16)a[2]; o[3]=(__bf16)a[3];
  o[4]=(__bf16)b[0]; o[5]=(__bf16)b[1]; o[6]=(__bf16)b[2]; o[7]=(__bf16)b[3];
  *(bf16x8*)(dst + base) = o;
}

// ---------------- merged QKV GEMM (proven 128^2 structure) --------------------
// A [M][C] bf16, Wqkv [3C][C] bf16 (rows 0..2047 = wq, 2048..4095 = wk, rest wv).
// Epilogue scatters by segment: Q -> [B*H][T][D]*qscale, K -> [B*H][T][D],
// V -> [B*H][D][T] (transposed).
__global__ __launch_bounds__(256, 3)
void gemm_qkv(const __bf16* __restrict__ A, const __bf16* __restrict__ W,
              const float* __restrict__ bq, const float* __restrict__ bk,
              const float* __restrict__ bv,
              __bf16* __restrict__ qb, __bf16* __restrict__ kb,
              __bf16* __restrict__ vb, float qscale)
{
  __shared__ __bf16 As[128 * 64];
  __shared__ __bf16 Bs[128 * 64];

  const int tid  = threadIdx.x;
  const int lane = tid & 63;
  const int wave = tid >> 6;
  const int wm = wave >> 1, wn = wave & 1;
  const int g  = lane >> 4;
  const int lr = lane & 15;
  const int row0 = blockIdx.x * 128;
  const int col0 = blockIdx.y * 128;   // 0..6016

  const int srow = lane >> 3;
  const int sblk = lane & 7;

  f32x4 acc[4][4] = {};

  for (int kt = 0; kt < Cz; kt += 64) {
    __syncthreads();
    #pragma unroll
    for (int p = 0; p < 4; ++p) {
      const int rb = p * 32 + wave * 8;
      const int r  = rb + srow;
      const int cb = sblk ^ (r & 7);
      gload_lds16(A + (size_t)(row0 + r) * Cz + kt + cb * 8, As + rb * 64);
      gload_lds16(W + (size_t)(col0 + r) * Cz + kt + cb * 8, Bs + rb * 64);
    }
    __syncthreads();
    #pragma unroll
    for (int kk = 0; kk < 2; ++kk) {
      bf16x8 af[4], bfr[4];
      #pragma unroll
      for (int i = 0; i < 4; ++i) {
        const int ar = wm * 64 + i * 16 + lr;
        af[i]  = *(const bf16x8*)(As + ar * 64 + ((((kk<<2)|g) ^ (ar & 7)) << 3));
        const int br = wn * 64 + i * 16 + lr;
        bfr[i] = *(const bf16x8*)(Bs + br * 64 + ((((kk<<2)|g) ^ (br & 7)) << 3));
      }
      #pragma unroll
      for (int i = 0; i < 4; ++i)
        #pragma unroll
        for (int j = 0; j < 4; ++j)
          acc[i][j] = __builtin_amdgcn_mfma_f32_16x16x32_bf16(af[i], bfr[j], acc[i][j], 0, 0, 0);
    }
  }

  const int seg  = col0 >> 11;          // 0:Q 1:K 2:V (block-uniform)
  const int csg0 = col0 & 2047;
  const float* bias = seg == 0 ? bq : (seg == 1 ? bk : bv);
  const float scl   = seg == 0 ? qscale : 1.0f;
  __bf16* outp      = seg == 0 ? qb : (seg == 1 ? kb : vb);

  #pragma unroll
  for (int j = 0; j < 4; ++j) {
    const int col = csg0 + wn * 64 + j * 16 + lr;   // 0..2047 within segment
    const float bvv = bias[col];
    #pragma unroll
    for (int i = 0; i < 4; ++i) {
      if (seg == 2) {
        const int row = row0 + wm * 64 + i * 16 + g * 4;
        const int b = row >> 11, t = row & (Tz - 1);
        const int h = col >> 7,  d = col & (Dd - 1);
        bf16x4 v4;
        #pragma unroll
        for (int r = 0; r < 4; ++r) v4[r] = (__bf16)(acc[i][j][r] + bvv);
        *(bf16x4*)(outp + ((size_t)(b * Hh + h) * Dd + d) * Tz + t) = v4;
      } else {
        #pragma unroll
        for (int r = 0; r < 4; ++r) {
          const int row = row0 + wm * 64 + i * 16 + g * 4 + r;
          const int b = row >> 11, t = row & (Tz - 1);
          const int h = col >> 7,  d = col & (Dd - 1);
          outp[((size_t)(b * Hh + h) * Tz + t) * Dd + d] = (__bf16)((acc[i][j][r] + bvv) * scl);
        }
      }
    }
  }
}

// ---------------- O-projection GEMM (f32 out) ----------------
__global__ __launch_bounds__(256, 3)
void gemm_o(const __bf16* __restrict__ A, const __bf16* __restrict__ W,
            const float* __restrict__ bias, float* __restrict__ Out)
{
  __shared__ __bf16 As[128 * 64];
  __shared__ __bf16 Bs[128 * 64];

  const int tid  = threadIdx.x;
  const int lane = tid & 63;
  const int wave = tid >> 6;
  const int wm = wave >> 1, wn = wave & 1;
  const int g  = lane >> 4;
  const int lr = lane & 15;
  const int row0 = blockIdx.x * 128;
  const int col0 = blockIdx.y * 128;

  const int srow = lane >> 3;
  const int sblk = lane & 7;

  f32x4 acc[4][4] = {};

  for (int kt = 0; kt < Cz; kt += 64) {
    __syncthreads();
    #pragma unroll
    for (int p = 0; p < 4; ++p) {
      const int rb = p * 32 + wave * 8;
      const int r  = rb + srow;
      const int cb = sblk ^ (r & 7);
      gload_lds16(A + (size_t)(row0 + r) * Cz + kt + cb * 8, As + rb * 64);
      gload_lds16(W + (size_t)(col0 + r) * Cz + kt + cb * 8, Bs + rb * 64);
    }
    __syncthreads();
    #pragma unroll
    for (int kk = 0; kk < 2; ++kk) {
      bf16x8 af[4], bfr[4];
      #pragma unroll
      for (int i = 0; i < 4; ++i) {
        const int ar = wm * 64 + i * 16 + lr;
        af[i]  = *(const bf16x8*)(As + ar * 64 + ((((kk<<2)|g) ^ (ar & 7)) << 3));
        const int br = wn * 64 + i * 16 + lr;
        bfr[i] = *(const bf16x8*)(Bs + br * 64 + ((((kk<<2)|g) ^ (br & 7)) << 3));
      }
      #pragma unroll
      for (int i = 0; i < 4; ++i)
        #pragma unroll
        for (int j = 0; j < 4; ++j)
          acc[i][j] = __builtin_amdgcn_mfma_f32_16x16x32_bf16(af[i], bfr[j], acc[i][j], 0, 0, 0);
    }
  }

  #pragma unroll
  for (int j = 0; j < 4; ++j) {
    const int col = col0 + wn * 64 + j * 16 + lr;
    const float bvv = bias[col];
    #pragma unroll
    for (int i = 0; i < 4; ++i)
      #pragma unroll
      for (int r = 0; r < 4; ++r) {
        const int row = row0 + wm * 64 + i * 16 + g * 4 + r;
        Out[(size_t)row * Cz + col] = acc[i][j][r] + bvv;
      }
  }
}

// ---------------- causal flash attention (swapped QK^T, R9 verified) ----------
// Q,K: [B*H][T][D] bf16 (Q pre-scaled by log2(e)/sqrt(D)). Vt: [B*H][D][T] bf16.
// O: [B*T][C] bf16. Grid (pair, qslot): pair FAST -> same-KV blocks share XCD.
__global__ __launch_bounds__(256, 2)
void attn_fwd(const __bf16* __restrict__ Q, const __bf16* __restrict__ Kg,
              const __bf16* __restrict__ Vt, __bf16* __restrict__ O)
{
  __shared__ __bf16 Ks[2][64 * 128];   // [kv][d], 16B-block XOR swizzle by (kv&7)
  __shared__ __bf16 Vs[2][128 * 64];   // [d][kv], 16B-block XOR swizzle by (d&7)
  __shared__ __bf16 Ps[4][32 * 64];    // per-wave P [32 q][64 kv], 8B-quad XOR by (q&3)<<2

  const int tid  = threadIdx.x;
  const int lane = tid & 63;
  const int wave = tid >> 6;
  const int g  = lane >> 4;
  const int lr = lane & 15;
  const int pair = blockIdx.x;
  const int bx   = blockIdx.y;
  const int b = pair >> 4, h = pair & 15;

  const __bf16* Qp = Q  + (size_t)pair * Tz * Dd;
  const __bf16* Kp = Kg + (size_t)pair * Tz * Dd;
  const __bf16* Vp = Vt + (size_t)pair * Dd * Tz;

  #define STAGE_KV(kv0_, buf_)                                                  \
    {                                                                           \
      const int kv0s = (kv0_);                                                  \
      _Pragma("unroll")                                                         \
      for (int p = 0; p < 4; ++p) {                                             \
        const int r  = p * 16 + wave * 4 + (lane >> 4);                         \
        const int cb = (lane & 15) ^ (r & 7);                                   \
        gload_lds16(Kp + (size_t)(kv0s + r) * Dd + cb * 8,                      \
                    &Ks[buf_][p * 2048 + wave * 512]);                          \
        const int d  = p * 32 + wave * 8 + (lane >> 3);                         \
        const int cv = (lane & 7) ^ (d & 7);                                    \
        gload_lds16(Vp + (size_t)d * Tz + kv0s + cv * 8,                        \
                    &Vs[buf_][p * 2048 + wave * 512]);                          \
      }                                                                         \
    }

  for (int pass = 0; pass < 2; ++pass) {
    const int qt  = pass == 0 ? (15 - bx) : bx;
    const int qw0 = qt * 128 + wave * 32;

    bf16x8 qf[2][4];
    #pragma unroll
    for (int im = 0; im < 2; ++im)
      #pragma unroll
      for (int ks = 0; ks < 4; ++ks)
        qf[im][ks] = *(const bf16x8*)(Qp + (size_t)(qw0 + im*16 + lr) * Dd + ks*32 + g*8);

    f32x4 oacc[2][8] = {};
    float mrow[2], lsum[2];
    mrow[0] = mrow[1] = -1e30f;
    lsum[0] = lsum[1] = 0.f;

    const int ntiles = 2 * qt + 2;

    STAGE_KV(0, 0);
    __syncthreads();

    for (int kt = 0; kt < ntiles; ++kt) {
      const int cur = kt & 1;
      const int kv0 = kt * 64;
      if (kt + 1 < ntiles) STAGE_KV((kt + 1) * 64, cur ^ 1);

      if (kv0 <= qw0 + 31) {
        f32x4 sacc[2][4] = {};
        __builtin_amdgcn_s_setprio(1);
        #pragma unroll
        for (int ks = 0; ks < 4; ++ks) {
          bf16x8 kf[4];
          #pragma unroll
          for (int in = 0; in < 4; ++in) {
            const int r = in*16 + lr;
            kf[in] = *(const bf16x8*)(&Ks[cur][r * 128 + ((((ks<<2)|g) ^ (r & 7)) << 3)]);
          }
          #pragma unroll
          for (int im = 0; im < 2; ++im)
            #pragma unroll
            for (int in = 0; in < 4; ++in)
              sacc[im][in] = __builtin_amdgcn_mfma_f32_16x16x32_bf16(kf[in], qf[im][ks], sacc[im][in], 0, 0, 0);
        }
        __builtin_amdgcn_s_setprio(0);

        if (kv0 + 63 > qw0) {
          #pragma unroll
          for (int im = 0; im < 2; ++im) {
            const int q = qw0 + im*16 + lr;
            #pragma unroll
            for (int in = 0; in < 4; ++in)
              #pragma unroll
              for (int r = 0; r < 4; ++r) {
                const int kv = kv0 + in*16 + g*4 + r;
                if (kv > q) sacc[im][in][r] = -3e38f;
              }
          }
        }

        #pragma unroll
        for (int im = 0; im < 2; ++im) {
          float m = fmaxf(fmaxf(sacc[im][0][0], sacc[im][0][1]),
                          fmaxf(sacc[im][0][2], sacc[im][0][3]));
          #pragma unroll
          for (int in = 1; in < 4; ++in)
            m = fmaxf(m, fmaxf(fmaxf(sacc[im][in][0], sacc[im][in][1]),
                               fmaxf(sacc[im][in][2], sacc[im][in][3])));
          m = fmaxf(m, __shfl_xor(m, 16));
          m = fmaxf(m, __shfl_xor(m, 32));

          const bool need = m > mrow[im] + 11.54f;
          if (__any(need)) {
            const float mn   = need ? m : mrow[im];
            const float corr = __builtin_amdgcn_exp2f(mrow[im] - mn);
            mrow[im] = mn;
            lsum[im] *= corr;
            const int sb = 20 * g;
            const float c0 = __shfl(corr, sb + 0);
            const float c1 = __shfl(corr, sb + 1);
            const float c2 = __shfl(corr, sb + 2);
            const float c3 = __shfl(corr, sb + 3);
            #pragma unroll
            for (int dn = 0; dn < 8; ++dn) {
              oacc[im][dn][0] *= c0; oacc[im][dn][1] *= c1;
              oacc[im][dn][2] *= c2; oacc[im][dn][3] *= c3;
            }
          }

          float rs = 0.f;
          const int prow = im*16 + lr;
          #pragma unroll
          for (int in = 0; in < 4; ++in) {
            const float p0 = __builtin_amdgcn_exp2f(sacc[im][in][0] - mrow[im]);
            const float p1 = __builtin_amdgcn_exp2f(sacc[im][in][1] - mrow[im]);
            const float p2 = __builtin_amdgcn_exp2f(sacc[im][in][2] - mrow[im]);
            const float p3 = __builtin_amdgcn_exp2f(sacc[im][in][3] - mrow[im]);
            rs += (p0 + p1) + (p2 + p3);
            bf16x4 q4;
            q4[0] = (__bf16)p0; q4[1] = (__bf16)p1;
            q4[2] = (__bf16)p2; q4[3] = (__bf16)p3;
            const int bs = (in*4 + g) ^ ((prow & 3) << 2);
            *(bf16x4*)(&Ps[wave][prow * 64 + bs * 4]) = q4;
          }
          rs += __shfl_xor(rs, 16);
          rs += __shfl_xor(rs, 32);
          lsum[im] += rs;
        }

        __builtin_amdgcn_s_setprio(1);
        #pragma unroll
        for (int kk = 0; kk < 2; ++kk) {
          bf16x8 pa[2];
          #pragma unroll
          for (int im = 0; im < 2; ++im) {
            const int prow = im*16 + lr;
            const int bs = (kk*8 + 2*g) ^ ((prow & 3) << 2);
            pa[im] = *(const bf16x8*)(&Ps[wave][prow * 64 + bs * 4]);
          }
          #pragma unroll
          for (int dn = 0; dn < 8; ++dn) {
            const int d = dn*16 + lr;
            bf16x8 vb = *(const bf16x8*)(&Vs[cur][d * 64 + ((((kk<<2)|g) ^ (d & 7)) << 3)]);
            #pragma unroll
            for (int im = 0; im < 2; ++im)
              oacc[im][dn] = __builtin_amdgcn_mfma_f32_16x16x32_bf16(pa[im], vb, oacc[im][dn], 0, 0, 0);
          }
        }
        __builtin_amdgcn_s_setprio(0);
      }
      __syncthreads();
    }

    #pragma unroll
    for (int im = 0; im < 2; ++im) {
      const float inv = 1.0f / lsum[im];
      const int sb = 20 * g;
      const float i0 = __shfl(inv, sb + 0);
      const float i1 = __shfl(inv, sb + 1);
      const float i2 = __shfl(inv, sb + 2);
      const float i3 = __shfl(inv, sb + 3);
      #pragma unroll
      for (int dn = 0; dn < 8; ++dn) {
        const int qrow = qw0 + im*16 + g*4;
        const int d    = h * Dd + dn*16 + lr;
        O[((size_t)(b * Tz + qrow + 0)) * Cz + d] = (__bf16)(oacc[im][dn][0] * i0);
        O[((size_t)(b * Tz + qrow + 1)) * Cz + d] = (__bf16)(oacc[im][dn][1] * i1);
        O[((size_t)(b * Tz + qrow + 2)) * Cz + d] = (__bf16)(oacc[im][dn][2] * i2);
        O[((size_t)(b * Tz + qrow + 3)) * Cz + d] = (__bf16)(oacc[im][dn][3] * i3);
      }
    }
  }
  #undef STAGE_KV
}

// ---------------- host launcher ----------------
extern "C" void kernel_launch(void* const* d_in, const int* in_sizes, int n_in,
                              void* d_out, int out_size, void* d_ws, size_t ws_size,
                              hipStream_t stream) {
  const float* x  = (const float*)d_in[0];
  const float* wq = (const float*)d_in[1];
  const float* bq = (const float*)d_in[2];
  const float* wk = (const float*)d_in[3];
  const float* bk = (const float*)d_in[4];
  const float* wv = (const float*)d_in[5];
  const float* bv = (const float*)d_in[6];
  const float* wo = (const float*)d_in[7];
  const float* bo = (const float*)d_in[8];
  float* out = (float*)d_out;

  char* w = (char*)d_ws;
  __bf16* xb   = (__bf16*)w; w += (size_t)Mm * Cz * 2;   // x bf16; reused as attn-out
  __bf16* wob  = (__bf16*)w; w += (size_t)Cz * Cz * 2;   // wo bf16
  __bf16* qb   = (__bf16*)w; w += (size_t)Mm * Cz * 2;
  __bf16* kb   = (__bf16*)w; w += (size_t)Mm * Cz * 2;
  __bf16* vbuf = (__bf16*)w; w += (size_t)Mm * Cz * 2;
  if (ws_size < (size_t)(w - (char*)d_ws)) return;

  // wqkv bf16 (24 MB) lives in d_out (64 MB f32): consumed by gemm_qkv long
  // before gemm_o overwrites d_out with the final output. Deterministic.
  __bf16* wqkv = (__bf16*)d_out;

  const int nx8 = Mm * Cz / 8;   // 2,097,152
  const int nw8 = Cz * Cz / 8;   //   524,288
  // 1/sqrt(128) * log2(e): softmax runs in exp2 domain
  const float qscale = 0.12752551286084110f;

  cvt_bf16<<<nx8 / 256, 256, 0, stream>>>(x, xb, nx8);
  cvt_w4<<<dim3(nw8 / 256, 4), 256, 0, stream>>>(wq, wk, wv, wo, wqkv, wob);

  gemm_qkv<<<dim3(Mm / 128, 48), 256, 0, stream>>>(xb, wqkv, bq, bk, bv,
                                                   qb, kb, vbuf, qscale);

  __bf16* ob = xb;   // attn output overwrites x (dead after gemm_qkv)
  attn_fwd<<<dim3(Bz * Hh, 8), 256, 0, stream>>>(qb, kb, vbuf, ob);

  gemm_o<<<dim3(Mm / 128, Cz / 128), 256, 0, stream>>>(ob, wob, bo, out);
}